// Round 8
// baseline (317.728 us; speedup 1.0000x reference)
//
#include <hip/hip_runtime.h>
#include <hip/hip_cooperative_groups.h>
#include <math.h>

namespace cg = cooperative_groups;

#define BB 8
#define TT 96
#define SS 192
#define DIN 512
#define DM 512

typedef short short8 __attribute__((ext_vector_type(8)));
typedef float f32x4 __attribute__((ext_vector_type(4)));

__device__ __forceinline__ unsigned short f2bf(float f) {
    unsigned int u = __float_as_uint(f);
    unsigned int r = u + 0x7FFFu + ((u >> 16) & 1u);   // RNE
    return (unsigned short)(r >> 16);
}
__device__ __forceinline__ float bf2f(unsigned short h) {
    return __uint_as_float(((unsigned int)h) << 16);
}

__device__ __forceinline__ void load_lds16(const void* g, void* l) {
    __builtin_amdgcn_global_load_lds((__attribute__((address_space(1))) void*)g,
                                     (__attribute__((address_space(3))) void*)l,
                                     16, 0, 0);
}

// ---- one 8-elem fp32->bf16 unit of the virtual concat of the 5 arrays ----
// bounds (elems): inputs [0,393216) mems [..,1179648) Wq [..,1441792)
//                 Wc [..,1703936) Wout [..,2228224)
__device__ __forceinline__ void prep_one(
    int idx,
    const float* __restrict__ inputs, const float* __restrict__ mems,
    const float* __restrict__ Wq, const float* __restrict__ Wc,
    const float* __restrict__ Wout,
    unsigned short* __restrict__ inputs_bf, unsigned short* __restrict__ mems_bf,
    unsigned short* __restrict__ Wq_bf, unsigned short* __restrict__ Wc_bf,
    unsigned short* __restrict__ Wout_bf)
{
    const float* s; unsigned short* d; int off;
    if (idx < 393216)       { s = inputs; d = inputs_bf; off = idx; }
    else if (idx < 1179648) { s = mems;   d = mems_bf;   off = idx - 393216; }
    else if (idx < 1441792) { s = Wq;     d = Wq_bf;     off = idx - 1179648; }
    else if (idx < 1703936) { s = Wc;     d = Wc_bf;     off = idx - 1441792; }
    else                    { s = Wout;   d = Wout_bf;   off = idx - 1703936; }
    float4 a = *(const float4*)(s + off);
    float4 b = *(const float4*)(s + off + 4);
    short8 o;
    o[0] = (short)f2bf(a.x); o[1] = (short)f2bf(a.y);
    o[2] = (short)f2bf(a.z); o[3] = (short)f2bf(a.w);
    o[4] = (short)f2bf(b.x); o[5] = (short)f2bf(b.y);
    o[6] = (short)f2bf(b.z); o[7] = (short)f2bf(b.w);
    *(short8*)(d + off) = o;
}

// ---------------- bf16 MFMA GEMM tile: triple-buffered counted-vmcnt --------
// out[m][n] = sum_k A[m][k]*W[n][k] ; 64x64 tile, 256 threads (4 waves),
// K-chunk 32, 3 LDS buffers, prefetch depth 2, global_load_lds width=16.
__device__ __forceinline__ void gemm_tile(
    unsigned short* As, unsigned short* Ws,   // shared, 3*2048 ushorts each
    const unsigned short* __restrict__ A, int lda,
    const unsigned short* __restrict__ W, int ldw,
    const float* __restrict__ bias,
    float* __restrict__ outF, unsigned short* __restrict__ outB,
    int bm, int bn, int N, int K)
{
    const int tid = threadIdx.x;
    const int r  = tid >> 2;          // 0..63 : tile row loaded by this thread
    const int kc = (tid & 3) * 8;     // k-offset within chunk
    const int lane = tid & 63, wv = tid >> 6;
    const int quad = lane >> 4, mrow = lane & 15;

    f32x4 acc0 = {0,0,0,0}, acc1 = {0,0,0,0}, acc2 = {0,0,0,0}, acc3 = {0,0,0,0};

    const unsigned short* arow = A + (size_t)(bm + r) * lda;
    const unsigned short* wrow = W + (size_t)(bn + r) * ldw;

    load_lds16(arow + kc,      As + tid * 8);
    load_lds16(wrow + kc,      Ws + tid * 8);
    load_lds16(arow + 32 + kc, As + 2048 + tid * 8);
    load_lds16(wrow + 32 + kc, Ws + 2048 + tid * 8);

    const int NC = K >> 5;
    int cur = 0;
    for (int c = 0; c < NC; ++c) {
        if (c + 2 < NC) {
            int nb = cur + 2; if (nb >= 3) nb -= 3;
            int gk = ((c + 2) << 5) + kc;
            load_lds16(arow + gk, As + nb * 2048 + tid * 8);
            load_lds16(wrow + gk, Ws + nb * 2048 + tid * 8);
            asm volatile("s_waitcnt vmcnt(4)" ::: "memory");
        } else if (c + 1 < NC) {
            asm volatile("s_waitcnt vmcnt(2)" ::: "memory");
        } else {
            asm volatile("s_waitcnt vmcnt(0)" ::: "memory");
        }
        __builtin_amdgcn_s_barrier();
        __builtin_amdgcn_sched_barrier(0);
        const unsigned short* Ab = As + cur * 2048;
        const unsigned short* Wb = Ws + cur * 2048;
        short8 av = *(const short8*)(Ab + (wv * 16 + mrow) * 32 + quad * 8);
        short8 b0 = *(const short8*)(Wb + (mrow) * 32 + quad * 8);
        short8 b1 = *(const short8*)(Wb + (16 + mrow) * 32 + quad * 8);
        short8 b2 = *(const short8*)(Wb + (32 + mrow) * 32 + quad * 8);
        short8 b3 = *(const short8*)(Wb + (48 + mrow) * 32 + quad * 8);
        acc0 = __builtin_amdgcn_mfma_f32_16x16x32_bf16(av, b0, acc0, 0, 0, 0);
        acc1 = __builtin_amdgcn_mfma_f32_16x16x32_bf16(av, b1, acc1, 0, 0, 0);
        acc2 = __builtin_amdgcn_mfma_f32_16x16x32_bf16(av, b2, acc2, 0, 0, 0);
        acc3 = __builtin_amdgcn_mfma_f32_16x16x32_bf16(av, b3, acc3, 0, 0, 0);
        __builtin_amdgcn_sched_barrier(0);
        __builtin_amdgcn_s_barrier();
        cur += 1; if (cur >= 3) cur -= 3;
    }

    f32x4 accs[4] = {acc0, acc1, acc2, acc3};
    #pragma unroll
    for (int ct = 0; ct < 4; ++ct) {
        int col = bn + ct * 16 + mrow;
        float bv = bias ? bias[col] : 0.0f;
        #pragma unroll
        for (int rg = 0; rg < 4; ++rg) {
            int rw = bm + wv * 16 + quad * 4 + rg;   // C/D: col=lane&15, row=quad*4+reg
            float val = accs[ct][rg] + bv;
            if (outF) outF[(size_t)rw * N + col] = val;
            else      outB[(size_t)rw * N + col] = f2bf(val);
        }
    }
}

// ---- proj dispatch table: 576 tile jobs ----
__device__ __forceinline__ void proj_dispatch(
    int bid, unsigned short* As, unsigned short* Ws,
    const unsigned short* __restrict__ inputs_bf,
    const unsigned short* __restrict__ mems_bf,
    const unsigned short* __restrict__ Wq_bf,
    const unsigned short* __restrict__ Wc_bf,
    const float* __restrict__ bc,
    const unsigned short* __restrict__ Wout_bf,
    const float* __restrict__ bout,
    unsigned short* __restrict__ wq_o, unsigned short* __restrict__ uh_o,
    unsigned short* __restrict__ m2_o, float* __restrict__ ih_o)
{
    if (bid < 96) {
        gemm_tile(As, Ws, inputs_bf, DIN, Wq_bf, DIN, nullptr, nullptr, wq_o,
                  (bid >> 3) * 64, (bid & 7) * 64, DM, DIN);
    } else if (bid < 288) {
        bid -= 96;
        gemm_tile(As, Ws, mems_bf, DM, Wc_bf, DM, bc, nullptr, uh_o,
                  (bid >> 3) * 64, (bid & 7) * 64, DM, DM);
    } else if (bid < 480) {
        bid -= 288;
        gemm_tile(As, Ws, mems_bf, DM, Wout_bf, DM + DIN, nullptr, nullptr, m2_o,
                  (bid >> 3) * 64, (bid & 7) * 64, DM, DM);
    } else {
        bid -= 480;
        gemm_tile(As, Ws, inputs_bf, DIN, Wout_bf + DM, DM + DIN, bout, ih_o, nullptr,
                  (bid >> 3) * 64, (bid & 7) * 64, DIN, DIN);
    }
}

// ---- attn body (R7-proven): scores+softmax+context(M2)+ih add -------------
__device__ __forceinline__ void attn_body(
    int row, float* s_align, float (*s_part)[DM], float* s_stat_p,
    const unsigned short* __restrict__ wq, const unsigned short* __restrict__ uh,
    const float* __restrict__ v, const unsigned short* __restrict__ m2,
    const float* __restrict__ ih, const int* __restrict__ masks,
    float* __restrict__ align_out, float* __restrict__ attn_h)
{
    const int b = row / TT;
    const int tid = threadIdx.x, lane = tid & 63, wid = tid >> 6;
    const int len = masks[b];
    const float C = 2.885390082f;   // 2/ln2

    if (tid >= len && tid < SS) s_align[tid] = -INFINITY;

    float cqf[8], vf[8];
    {
        short8 q = *(const short8*)(wq + (size_t)row * DM + lane * 8);
        float4 v0 = *(const float4*)(v + lane * 8);
        float4 v1 = *(const float4*)(v + lane * 8 + 4);
        #pragma unroll
        for (int j = 0; j < 8; ++j) cqf[j] = bf2f((unsigned short)q[j]) * C;
        vf[0] = v0.x; vf[1] = v0.y; vf[2] = v0.z; vf[3] = v0.w;
        vf[4] = v1.x; vf[5] = v1.y; vf[6] = v1.z; vf[7] = v1.w;
    }
    float SV = ((vf[0] + vf[1]) + (vf[2] + vf[3])) +
               ((vf[4] + vf[5]) + (vf[6] + vf[7]));
    #pragma unroll
    for (int off = 32; off; off >>= 1) SV += __shfl_xor(SV, off);

    #pragma unroll 2
    for (int s = wid; s < len; s += 4) {
        short8 u = *(const short8*)(uh + ((size_t)b * SS + s) * DM + lane * 8);
        float pr = 0.f;
        #pragma unroll
        for (int j = 0; j < 8; ++j) {
            float e = __builtin_amdgcn_exp2f(
                fmaf(bf2f((unsigned short)u[j]), C, cqf[j]));
            float rc = __builtin_amdgcn_rcpf(e + 1.f);
            pr = fmaf(vf[j], rc, pr);
        }
        #pragma unroll
        for (int off = 32; off; off >>= 1)
            pr += __shfl_xor(pr, off);
        if (lane == 0) s_align[s] = fmaf(-2.f, pr, SV);
    }
    __syncthreads();

    if (tid < 64) {
        float m = fmaxf(fmaxf(s_align[tid], s_align[tid + 64]), s_align[tid + 128]);
        #pragma unroll
        for (int off = 32; off; off >>= 1) m = fmaxf(m, __shfl_xor(m, off));
        float e0 = __builtin_amdgcn_exp2f((s_align[tid]       - m) * 1.44269504f);
        float e1 = __builtin_amdgcn_exp2f((s_align[tid + 64]  - m) * 1.44269504f);
        float e2 = __builtin_amdgcn_exp2f((s_align[tid + 128] - m) * 1.44269504f);
        s_align[tid] = e0; s_align[tid + 64] = e1; s_align[tid + 128] = e2;
        float sum = e0 + e1 + e2;
        #pragma unroll
        for (int off = 32; off; off >>= 1) sum += __shfl_xor(sum, off);
        if (tid == 0) s_stat_p[0] = 1.0f / sum;
    }
    __syncthreads();
    const float inv = s_stat_p[0];
    if (tid < SS) align_out[(size_t)row * SS + tid] = s_align[tid] * inv;

    const int sbase = wid * 48;
    int nloc = len - sbase;
    nloc = nloc < 0 ? 0 : (nloc > 48 ? 48 : nloc);
    float accv[8] = {0,0,0,0,0,0,0,0};
    const unsigned short* m2b = m2 + ((size_t)b * SS + sbase) * DM + lane * 8;
    #pragma unroll 4
    for (int i = 0; i < nloc; ++i) {
        float p = s_align[sbase + i];
        short8 mv = *(const short8*)(m2b + (size_t)i * DM);
        #pragma unroll
        for (int j = 0; j < 8; ++j)
            accv[j] = fmaf(p, bf2f((unsigned short)mv[j]), accv[j]);
    }
    {
        float4 t0; t0.x = accv[0]; t0.y = accv[1]; t0.z = accv[2]; t0.w = accv[3];
        float4 t1; t1.x = accv[4]; t1.y = accv[5]; t1.z = accv[6]; t1.w = accv[7];
        *(float4*)&s_part[wid][lane * 8]     = t0;
        *(float4*)&s_part[wid][lane * 8 + 4] = t1;
    }
    __syncthreads();

    const int d0 = tid * 2;
    float r0 = s_part[0][d0]     + s_part[1][d0]     + s_part[2][d0]     + s_part[3][d0];
    float r1 = s_part[0][d0 + 1] + s_part[1][d0 + 1] + s_part[2][d0 + 1] + s_part[3][d0 + 1];
    float2 ihv = *(const float2*)(ih + (size_t)row * DIN + d0);
    float2 o;
    o.x = fmaf(r0, inv, ihv.x);
    o.y = fmaf(r1, inv, ihv.y);
    *(float2*)(attn_h + (size_t)row * DIN + d0) = o;
}

// =================== fused cooperative kernel (768 blocks) ==================
// phase 0: prep cvt  -> grid.sync -> phase 1: proj (576 jobs) -> grid.sync ->
// phase 2: attn (row = blockIdx.x). LDS (24KB) reused across phases.
__global__ __launch_bounds__(256, 3) void fused_all(
    const float* __restrict__ inputs, const float* __restrict__ mems,
    const int* __restrict__ masks,
    const float* __restrict__ Wq, const float* __restrict__ Wc,
    const float* __restrict__ bc, const float* __restrict__ v,
    const float* __restrict__ Wout, const float* __restrict__ bout,
    unsigned short* __restrict__ inputs_bf, unsigned short* __restrict__ mems_bf,
    unsigned short* __restrict__ Wq_bf, unsigned short* __restrict__ Wc_bf,
    unsigned short* __restrict__ Wout_bf,
    unsigned short* __restrict__ wq_bf, unsigned short* __restrict__ uh_bf,
    unsigned short* __restrict__ m2_bf, float* __restrict__ ih,
    float* __restrict__ align_out, float* __restrict__ attn_h)
{
    __shared__ __align__(16) unsigned char smem[24576];
    cg::grid_group grid = cg::this_grid();
    const int bid = blockIdx.x, tid = threadIdx.x;

    // phase 0: 2228224/8 = 278528 units over 196608 threads (2 iters)
    for (int u8 = bid * 256 + tid; u8 < 278528; u8 += 768 * 256)
        prep_one(u8 * 8, inputs, mems, Wq, Wc, Wout,
                 inputs_bf, mems_bf, Wq_bf, Wc_bf, Wout_bf);
    grid.sync();

    // phase 1: proj
    if (bid < 576) {
        unsigned short* As = (unsigned short*)smem;
        unsigned short* Ws = As + 3 * 2048;
        proj_dispatch(bid, As, Ws, inputs_bf, mems_bf, Wq_bf, Wc_bf, bc,
                      Wout_bf, bout, wq_bf, uh_bf, m2_bf, ih);
    }
    grid.sync();

    // phase 2: attn
    {
        float* s_align = (float*)smem;                       // 768 B
        float (*s_part)[DM] = (float(*)[DM])(smem + 1024);   // 8 KB
        float* s_stat_p = (float*)(smem + 1024 + 8192);      // 4 B
        attn_body(bid, s_align, s_part, s_stat_p,
                  wq_bf, uh_bf, v, m2_bf, ih, masks, align_out, attn_h);
    }
}

// =================== fallback 3-kernel path (R7-proven) =====================
__global__ __launch_bounds__(256) void prep_cvt(
    const float* __restrict__ inputs, const float* __restrict__ mems,
    const float* __restrict__ Wq, const float* __restrict__ Wc,
    const float* __restrict__ Wout,
    unsigned short* __restrict__ inputs_bf, unsigned short* __restrict__ mems_bf,
    unsigned short* __restrict__ Wq_bf, unsigned short* __restrict__ Wc_bf,
    unsigned short* __restrict__ Wout_bf)
{
    int u8 = blockIdx.x * 256 + threadIdx.x;   // grid 1088 covers 278528 units
    if (u8 < 278528)
        prep_one(u8 * 8, inputs, mems, Wq, Wc, Wout,
                 inputs_bf, mems_bf, Wq_bf, Wc_bf, Wout_bf);
}

__global__ __launch_bounds__(256) void proj_gemm(
    const unsigned short* __restrict__ inputs_bf,
    const unsigned short* __restrict__ mems_bf,
    const unsigned short* __restrict__ Wq_bf,
    const unsigned short* __restrict__ Wc_bf,
    const float* __restrict__ bc,
    const unsigned short* __restrict__ Wout_bf,
    const float* __restrict__ bout,
    unsigned short* __restrict__ wq_o, unsigned short* __restrict__ uh_o,
    unsigned short* __restrict__ m2_o, float* __restrict__ ih_o)
{
    __shared__ __align__(16) unsigned short As[3 * 2048];
    __shared__ __align__(16) unsigned short Ws[3 * 2048];
    proj_dispatch(blockIdx.x, As, Ws, inputs_bf, mems_bf, Wq_bf, Wc_bf, bc,
                  Wout_bf, bout, wq_o, uh_o, m2_o, ih_o);
}

__global__ __launch_bounds__(256) void attn_core(
    const unsigned short* __restrict__ wq, const unsigned short* __restrict__ uh,
    const float* __restrict__ v, const unsigned short* __restrict__ m2,
    const float* __restrict__ ih, const int* __restrict__ masks,
    float* __restrict__ align_out, float* __restrict__ attn_h)
{
    __shared__ float s_align[SS];
    __shared__ __align__(16) float s_part[4][DM];
    __shared__ float s_stat;
    attn_body(blockIdx.x, s_align, s_part, &s_stat,
              wq, uh, v, m2, ih, masks, align_out, attn_h);
}

extern "C" void kernel_launch(void* const* d_in, const int* in_sizes, int n_in,
                              void* d_out, int out_size, void* d_ws, size_t ws_size,
                              hipStream_t stream) {
    (void)in_sizes; (void)n_in; (void)out_size; (void)ws_size;
    const float* inputs = (const float*)d_in[0];
    const float* mems   = (const float*)d_in[1];
    const int*   masks  = (const int*)  d_in[2];
    const float* Wq     = (const float*)d_in[3];
    const float* Wc     = (const float*)d_in[4];
    const float* bc     = (const float*)d_in[5];
    const float* v      = (const float*)d_in[6];
    const float* Wout   = (const float*)d_in[7];
    const float* bout   = (const float*)d_in[8];

    unsigned short* p = (unsigned short*)d_ws;
    unsigned short* inputs_bf = p;        p += 393216;
    unsigned short* mems_bf   = p;        p += 786432;
    unsigned short* Wq_bf     = p;        p += 262144;
    unsigned short* Wc_bf     = p;        p += 262144;
    unsigned short* Wout_bf   = p;        p += 524288;
    unsigned short* uh_bf     = p;        p += 786432;
    unsigned short* wq_bf     = p;        p += 393216;
    unsigned short* m2_bf     = p;        p += 786432;
    float* ih                 = (float*)p;

    float* attn_h    = (float*)d_out;                    // [768][512]
    float* align_out = attn_h + (size_t)BB * TT * DIN;   // [768][192]

    void* args[] = {
        (void*)&inputs, (void*)&mems, (void*)&masks,
        (void*)&Wq, (void*)&Wc, (void*)&bc, (void*)&v,
        (void*)&Wout, (void*)&bout,
        (void*)&inputs_bf, (void*)&mems_bf, (void*)&Wq_bf, (void*)&Wc_bf,
        (void*)&Wout_bf, (void*)&wq_bf, (void*)&uh_bf, (void*)&m2_bf,
        (void*)&ih, (void*)&align_out, (void*)&attn_h };

    hipError_t e = hipLaunchCooperativeKernel(
        reinterpret_cast<void*>(fused_all), dim3(768), dim3(256),
        args, 0u, stream);

    if (e != hipSuccess) {
        // fallback: proven 3-kernel path
        prep_cvt<<<1088, 256, 0, stream>>>(inputs, mems, Wq, Wc, Wout,
                                           inputs_bf, mems_bf, Wq_bf, Wc_bf, Wout_bf);
        proj_gemm<<<576, 256, 0, stream>>>(inputs_bf, mems_bf, Wq_bf, Wc_bf, bc,
                                           Wout_bf, bout, wq_bf, uh_bf, m2_bf, ih);
        attn_core<<<BB * TT, 256, 0, stream>>>(wq_bf, uh_bf, v, m2_bf, ih, masks,
                                               align_out, attn_h);
    }
}

// Round 9
// 109.521 us; speedup vs baseline: 2.9011x; 2.9011x over previous
//
#include <hip/hip_runtime.h>
#include <math.h>

#define BB 8
#define TT 96
#define SS 192
#define DIN 512
#define DM 512

typedef short short8 __attribute__((ext_vector_type(8)));
typedef float f32x4 __attribute__((ext_vector_type(4)));

__device__ __forceinline__ unsigned short f2bf(float f) {
    unsigned int u = __float_as_uint(f);
    unsigned int r = u + 0x7FFFu + ((u >> 16) & 1u);   // RNE
    return (unsigned short)(r >> 16);
}
__device__ __forceinline__ float bf2f(unsigned short h) {
    return __uint_as_float(((unsigned int)h) << 16);
}

__device__ __forceinline__ void load_lds16(const void* g, void* l) {
    __builtin_amdgcn_global_load_lds((__attribute__((address_space(1))) void*)g,
                                     (__attribute__((address_space(3))) void*)l,
                                     16, 0, 0);
}

// ---------------- prep: fp32 -> bf16 conversion of 5 arrays ----------------
__global__ __launch_bounds__(256) void prep_cvt(
    const float* __restrict__ s0, const float* __restrict__ s1,
    const float* __restrict__ s2, const float* __restrict__ s3,
    const float* __restrict__ s4,
    unsigned short* __restrict__ d0, unsigned short* __restrict__ d1,
    unsigned short* __restrict__ d2, unsigned short* __restrict__ d3,
    unsigned short* __restrict__ d4)
{
    int bid = blockIdx.x;
    const float* s; unsigned short* d; int base;
    if (bid < 192)      { s = s0; d = d0; base = bid * 2048; }
    else if (bid < 576) { s = s1; d = d1; base = (bid - 192) * 2048; }
    else if (bid < 704) { s = s2; d = d2; base = (bid - 576) * 2048; }
    else if (bid < 832) { s = s3; d = d3; base = (bid - 704) * 2048; }
    else                { s = s4; d = d4; base = (bid - 832) * 2048; }
    int idx = base + threadIdx.x * 8;
    float4 a = *(const float4*)(s + idx);
    float4 b = *(const float4*)(s + idx + 4);
    short8 o;
    o[0] = (short)f2bf(a.x); o[1] = (short)f2bf(a.y);
    o[2] = (short)f2bf(a.z); o[3] = (short)f2bf(a.w);
    o[4] = (short)f2bf(b.x); o[5] = (short)f2bf(b.y);
    o[6] = (short)f2bf(b.z); o[7] = (short)f2bf(b.w);
    *(short8*)(d + idx) = o;
}

// ---------------- bf16 MFMA GEMM tile: triple-buffered counted-vmcnt --------
__device__ __forceinline__ void gemm_tile(
    unsigned short* As, unsigned short* Ws,   // shared, 3*2048 ushorts each
    const unsigned short* __restrict__ A, int lda,
    const unsigned short* __restrict__ W, int ldw,
    const float* __restrict__ bias,
    float* __restrict__ outF, unsigned short* __restrict__ outB,
    int bm, int bn, int N, int K)
{
    const int tid = threadIdx.x;
    const int r  = tid >> 2;
    const int kc = (tid & 3) * 8;
    const int lane = tid & 63, wv = tid >> 6;
    const int quad = lane >> 4, mrow = lane & 15;

    f32x4 acc0 = {0,0,0,0}, acc1 = {0,0,0,0}, acc2 = {0,0,0,0}, acc3 = {0,0,0,0};

    const unsigned short* arow = A + (size_t)(bm + r) * lda;
    const unsigned short* wrow = W + (size_t)(bn + r) * ldw;

    load_lds16(arow + kc,      As + tid * 8);
    load_lds16(wrow + kc,      Ws + tid * 8);
    load_lds16(arow + 32 + kc, As + 2048 + tid * 8);
    load_lds16(wrow + 32 + kc, Ws + 2048 + tid * 8);

    const int NC = K >> 5;
    int cur = 0;
    for (int c = 0; c < NC; ++c) {
        if (c + 2 < NC) {
            int nb = cur + 2; if (nb >= 3) nb -= 3;
            int gk = ((c + 2) << 5) + kc;
            load_lds16(arow + gk, As + nb * 2048 + tid * 8);
            load_lds16(wrow + gk, Ws + nb * 2048 + tid * 8);
            asm volatile("s_waitcnt vmcnt(4)" ::: "memory");
        } else if (c + 1 < NC) {
            asm volatile("s_waitcnt vmcnt(2)" ::: "memory");
        } else {
            asm volatile("s_waitcnt vmcnt(0)" ::: "memory");
        }
        __builtin_amdgcn_s_barrier();
        __builtin_amdgcn_sched_barrier(0);
        const unsigned short* Ab = As + cur * 2048;
        const unsigned short* Wb = Ws + cur * 2048;
        short8 av = *(const short8*)(Ab + (wv * 16 + mrow) * 32 + quad * 8);
        short8 b0 = *(const short8*)(Wb + (mrow) * 32 + quad * 8);
        short8 b1 = *(const short8*)(Wb + (16 + mrow) * 32 + quad * 8);
        short8 b2 = *(const short8*)(Wb + (32 + mrow) * 32 + quad * 8);
        short8 b3 = *(const short8*)(Wb + (48 + mrow) * 32 + quad * 8);
        acc0 = __builtin_amdgcn_mfma_f32_16x16x32_bf16(av, b0, acc0, 0, 0, 0);
        acc1 = __builtin_amdgcn_mfma_f32_16x16x32_bf16(av, b1, acc1, 0, 0, 0);
        acc2 = __builtin_amdgcn_mfma_f32_16x16x32_bf16(av, b2, acc2, 0, 0, 0);
        acc3 = __builtin_amdgcn_mfma_f32_16x16x32_bf16(av, b3, acc3, 0, 0, 0);
        __builtin_amdgcn_sched_barrier(0);
        __builtin_amdgcn_s_barrier();
        cur += 1; if (cur >= 3) cur -= 3;
    }

    f32x4 accs[4] = {acc0, acc1, acc2, acc3};
    #pragma unroll
    for (int ct = 0; ct < 4; ++ct) {
        int col = bn + ct * 16 + mrow;
        float bv = bias ? bias[col] : 0.0f;
        #pragma unroll
        for (int rg = 0; rg < 4; ++rg) {
            int rw = bm + wv * 16 + quad * 4 + rg;   // C/D: col=lane&15, row=quad*4+reg
            float val = accs[ct][rg] + bv;
            if (outF) outF[(size_t)rw * N + col] = val;
            else      outB[(size_t)rw * N + col] = f2bf(val);
        }
    }
}

// ---------------- fused projections: 4 segments, 576 blocks -----------------
__global__ __launch_bounds__(256) void proj_gemm(
    const unsigned short* __restrict__ inputs_bf,
    const unsigned short* __restrict__ mems_bf,
    const unsigned short* __restrict__ Wq_bf,
    const unsigned short* __restrict__ Wc_bf,
    const float* __restrict__ bc,
    const unsigned short* __restrict__ Wout_bf,
    const float* __restrict__ bout,
    unsigned short* __restrict__ wq_o, unsigned short* __restrict__ uh_o,
    unsigned short* __restrict__ m2_o, float* __restrict__ ih_o)
{
    __shared__ __align__(16) unsigned short As[3 * 2048];
    __shared__ __align__(16) unsigned short Ws[3 * 2048];
    int bid = blockIdx.x;
    if (bid < 96) {
        gemm_tile(As, Ws, inputs_bf, DIN, Wq_bf, DIN, nullptr, nullptr, wq_o,
                  (bid >> 3) * 64, (bid & 7) * 64, DM, DIN);
    } else if (bid < 288) {
        bid -= 96;
        gemm_tile(As, Ws, mems_bf, DM, Wc_bf, DM, bc, nullptr, uh_o,
                  (bid >> 3) * 64, (bid & 7) * 64, DM, DM);
    } else if (bid < 480) {
        bid -= 288;
        gemm_tile(As, Ws, mems_bf, DM, Wout_bf, DM + DIN, nullptr, nullptr, m2_o,
                  (bid >> 3) * 64, (bid & 7) * 64, DM, DM);
    } else {
        bid -= 480;
        gemm_tile(As, Ws, inputs_bf, DIN, Wout_bf + DM, DM + DIN, bout, ih_o, nullptr,
                  (bid >> 3) * 64, (bid & 7) * 64, DIN, DIN);
    }
}

// ---------------- fused scores + softmax + context(M2) + ih add -------------
// scores: two s-values per wave-iteration (s, s+4) with independent loads and
// independent reduce chains -> 2x memory-level parallelism (R3 showed VGPR=20,
// i.e. single-chain serialization at ~L2 latency per s).
__global__ __launch_bounds__(256) void attn_core(
    const unsigned short* __restrict__ wq,     // [B*T][DM] bf16
    const unsigned short* __restrict__ uh,     // [B*S][DM] bf16
    const float* __restrict__ v,               // [DM] fp32
    const unsigned short* __restrict__ m2,     // [B*S][DM] bf16
    const float* __restrict__ ih,              // [B*T][DIN] fp32 (incl bout)
    const int* __restrict__ masks,             // [B]
    float* __restrict__ align_out,             // [B*T][S] fp32
    float* __restrict__ attn_h)                // [B*T][DIN] fp32
{
    __shared__ float s_align[SS];
    __shared__ __align__(16) float s_part[4][DM];
    __shared__ float s_stat;
    const int row = blockIdx.x, b = row / TT;
    const int tid = threadIdx.x, lane = tid & 63, wid = tid >> 6;
    const int len = masks[b];
    const float C = 2.885390082f;   // 2/ln2

    // masked tail of s_align -> -INF (writers disjoint from scores loop)
    if (tid >= len && tid < SS) s_align[tid] = -INFINITY;

    float cqf[8], vf[8];
    {
        short8 q = *(const short8*)(wq + (size_t)row * DM + lane * 8);
        float4 v0 = *(const float4*)(v + lane * 8);
        float4 v1 = *(const float4*)(v + lane * 8 + 4);
        #pragma unroll
        for (int j = 0; j < 8; ++j) cqf[j] = bf2f((unsigned short)q[j]) * C;
        vf[0] = v0.x; vf[1] = v0.y; vf[2] = v0.z; vf[3] = v0.w;
        vf[4] = v1.x; vf[5] = v1.y; vf[6] = v1.z; vf[7] = v1.w;
    }
    float SV = ((vf[0] + vf[1]) + (vf[2] + vf[3])) +
               ((vf[4] + vf[5]) + (vf[6] + vf[7]));
    #pragma unroll
    for (int off = 32; off; off >>= 1) SV += __shfl_xor(SV, off);

    const unsigned short* ub = uh + (size_t)b * SS * DM + lane * 8;
    for (int s = wid; s < len; s += 8) {
        const int s1 = s + 4;
        const bool has2 = s1 < len;
        // independent loads for both rows issue back-to-back
        short8 u0 = *(const short8*)(ub + (size_t)s * DM);
        short8 u1 = has2 ? *(const short8*)(ub + (size_t)s1 * DM) : u0;
        float pr0 = 0.f, pr1 = 0.f;
        #pragma unroll
        for (int j = 0; j < 8; ++j) {
            float e0 = __builtin_amdgcn_exp2f(
                fmaf(bf2f((unsigned short)u0[j]), C, cqf[j]));
            float e1 = __builtin_amdgcn_exp2f(
                fmaf(bf2f((unsigned short)u1[j]), C, cqf[j]));
            pr0 = fmaf(vf[j], __builtin_amdgcn_rcpf(e0 + 1.f), pr0);
            pr1 = fmaf(vf[j], __builtin_amdgcn_rcpf(e1 + 1.f), pr1);
        }
        // two independent shuffle-reduce chains, interleaved
        #pragma unroll
        for (int off = 32; off; off >>= 1) {
            pr0 += __shfl_xor(pr0, off);
            pr1 += __shfl_xor(pr1, off);
        }
        if (lane == 0) {
            s_align[s] = fmaf(-2.f, pr0, SV);
            if (has2) s_align[s1] = fmaf(-2.f, pr1, SV);
        }
    }
    __syncthreads();

    if (tid < 64) {
        float m = fmaxf(fmaxf(s_align[tid], s_align[tid + 64]), s_align[tid + 128]);
        #pragma unroll
        for (int off = 32; off; off >>= 1) m = fmaxf(m, __shfl_xor(m, off));
        float e0 = __builtin_amdgcn_exp2f((s_align[tid]       - m) * 1.44269504f);
        float e1 = __builtin_amdgcn_exp2f((s_align[tid + 64]  - m) * 1.44269504f);
        float e2 = __builtin_amdgcn_exp2f((s_align[tid + 128] - m) * 1.44269504f);
        s_align[tid] = e0; s_align[tid + 64] = e1; s_align[tid + 128] = e2;
        float sum = e0 + e1 + e2;
        #pragma unroll
        for (int off = 32; off; off >>= 1) sum += __shfl_xor(sum, off);
        if (tid == 0) s_stat = 1.0f / sum;
    }
    __syncthreads();
    const float inv = s_stat;
    if (tid < SS) align_out[(size_t)row * SS + tid] = s_align[tid] * inv;

    // ---- context partials: wave wid covers s in [wid*48, wid*48+nloc) ----
    const int sbase = wid * 48;
    int nloc = len - sbase;
    nloc = nloc < 0 ? 0 : (nloc > 48 ? 48 : nloc);
    float accv[8] = {0,0,0,0,0,0,0,0};
    const unsigned short* m2b = m2 + ((size_t)b * SS + sbase) * DM + lane * 8;
    #pragma unroll 8
    for (int i = 0; i < nloc; ++i) {
        float p = s_align[sbase + i];
        short8 mv = *(const short8*)(m2b + (size_t)i * DM);
        #pragma unroll
        for (int j = 0; j < 8; ++j)
            accv[j] = fmaf(p, bf2f((unsigned short)mv[j]), accv[j]);
    }
    {
        float4 t0; t0.x = accv[0]; t0.y = accv[1]; t0.z = accv[2]; t0.w = accv[3];
        float4 t1; t1.x = accv[4]; t1.y = accv[5]; t1.z = accv[6]; t1.w = accv[7];
        *(float4*)&s_part[wid][lane * 8]     = t0;
        *(float4*)&s_part[wid][lane * 8 + 4] = t1;
    }
    __syncthreads();

    const int d0 = tid * 2;
    float r0 = s_part[0][d0]     + s_part[1][d0]     + s_part[2][d0]     + s_part[3][d0];
    float r1 = s_part[0][d0 + 1] + s_part[1][d0 + 1] + s_part[2][d0 + 1] + s_part[3][d0 + 1];
    float2 ihv = *(const float2*)(ih + (size_t)row * DIN + d0);
    float2 o;
    o.x = fmaf(r0, inv, ihv.x);
    o.y = fmaf(r1, inv, ihv.y);
    *(float2*)(attn_h + (size_t)row * DIN + d0) = o;
}

extern "C" void kernel_launch(void* const* d_in, const int* in_sizes, int n_in,
                              void* d_out, int out_size, void* d_ws, size_t ws_size,
                              hipStream_t stream) {
    (void)in_sizes; (void)n_in; (void)out_size; (void)ws_size;
    const float* inputs = (const float*)d_in[0];
    const float* mems   = (const float*)d_in[1];
    const int*   masks  = (const int*)  d_in[2];
    const float* Wq     = (const float*)d_in[3];
    const float* Wc     = (const float*)d_in[4];
    const float* bc     = (const float*)d_in[5];
    const float* v      = (const float*)d_in[6];
    const float* Wout   = (const float*)d_in[7];
    const float* bout   = (const float*)d_in[8];

    unsigned short* p = (unsigned short*)d_ws;
    unsigned short* inputs_bf = p;        p += 393216;   // B*T*DIN
    unsigned short* mems_bf   = p;        p += 786432;   // B*S*DM
    unsigned short* Wq_bf     = p;        p += 262144;
    unsigned short* Wc_bf     = p;        p += 262144;
    unsigned short* Wout_bf   = p;        p += 524288;
    unsigned short* uh_bf     = p;        p += 786432;
    unsigned short* wq_bf     = p;        p += 393216;
    unsigned short* m2_bf     = p;        p += 786432;
    float* ih                 = (float*)p;               // [768][512] fp32, 16B-aligned

    float* attn_h    = (float*)d_out;                    // [768][512]
    float* align_out = attn_h + (size_t)BB * TT * DIN;   // [768][192]

    prep_cvt<<<1088, 256, 0, stream>>>(inputs, mems, Wq, Wc, Wout,
                                       inputs_bf, mems_bf, Wq_bf, Wc_bf, Wout_bf);
    proj_gemm<<<576, 256, 0, stream>>>(inputs_bf, mems_bf, Wq_bf, Wc_bf, bc,
                                       Wout_bf, bout, wq_bf, uh_bf, m2_bf, ih);
    attn_core<<<BB * TT, 256, 0, stream>>>(wq_bf, uh_bf, v, m2_bf, ih, masks,
                                           align_out, attn_h);
}

// Round 10
// 106.616 us; speedup vs baseline: 2.9801x; 1.0273x over previous
//
#include <hip/hip_runtime.h>
#include <math.h>

#define BB 8
#define TT 96
#define SS 192
#define DIN 512
#define DM 512

typedef short short8 __attribute__((ext_vector_type(8)));
typedef float f32x4 __attribute__((ext_vector_type(4)));

__device__ __forceinline__ unsigned short f2bf(float f) {
    unsigned int u = __float_as_uint(f);
    unsigned int r = u + 0x7FFFu + ((u >> 16) & 1u);   // RNE
    return (unsigned short)(r >> 16);
}
__device__ __forceinline__ float bf2f(unsigned short h) {
    return __uint_as_float(((unsigned int)h) << 16);
}

__device__ __forceinline__ void load_lds16(const void* g, void* l) {
    __builtin_amdgcn_global_load_lds((__attribute__((address_space(1))) void*)g,
                                     (__attribute__((address_space(3))) void*)l,
                                     16, 0, 0);
}

// ---------------- prep: fp32 -> bf16 conversion of 5 arrays ----------------
__global__ __launch_bounds__(256) void prep_cvt(
    const float* __restrict__ s0, const float* __restrict__ s1,
    const float* __restrict__ s2, const float* __restrict__ s3,
    const float* __restrict__ s4,
    unsigned short* __restrict__ d0, unsigned short* __restrict__ d1,
    unsigned short* __restrict__ d2, unsigned short* __restrict__ d3,
    unsigned short* __restrict__ d4)
{
    int bid = blockIdx.x;
    const float* s; unsigned short* d; int base;
    if (bid < 192)      { s = s0; d = d0; base = bid * 2048; }
    else if (bid < 576) { s = s1; d = d1; base = (bid - 192) * 2048; }
    else if (bid < 704) { s = s2; d = d2; base = (bid - 576) * 2048; }
    else if (bid < 832) { s = s3; d = d3; base = (bid - 704) * 2048; }
    else                { s = s4; d = d4; base = (bid - 832) * 2048; }
    int idx = base + threadIdx.x * 8;
    float4 a = *(const float4*)(s + idx);
    float4 b = *(const float4*)(s + idx + 4);
    short8 o;
    o[0] = (short)f2bf(a.x); o[1] = (short)f2bf(a.y);
    o[2] = (short)f2bf(a.z); o[3] = (short)f2bf(a.w);
    o[4] = (short)f2bf(b.x); o[5] = (short)f2bf(b.y);
    o[6] = (short)f2bf(b.z); o[7] = (short)f2bf(b.w);
    *(short8*)(d + idx) = o;
}

// ---------------- bf16 MFMA GEMM tile: BK=64, double-buffered, counted ------
// out[m][n] = sum_k A[m][k]*W[n][k] ; 64x64 tile, 256 threads (4 waves),
// 2 chunks (BK=64) per barrier-phase -> 16 barriers/block (was 32).
// Per iter: 4 staging ops/thread (2A+2W); steady-state s_waitcnt vmcnt(4)
// keeps next iter's 4 in flight across the barrier.
// Hazard: iter i writes buf (i+1)%2; that buf was last read in iter i-1,
// strictly before its end barrier, which precedes iter i's issue. Safe.
__device__ __forceinline__ void gemm_tile(
    unsigned short* As, unsigned short* Ws,   // shared, 2*4096 ushorts each
    const unsigned short* __restrict__ A, int lda,
    const unsigned short* __restrict__ W, int ldw,
    const float* __restrict__ bias,
    float* __restrict__ outF, unsigned short* __restrict__ outB,
    int bm, int bn, int N, int K)
{
    const int tid = threadIdx.x;
    const int r  = tid >> 2;          // 0..63 : tile row loaded by this thread
    const int kc = (tid & 3) * 8;     // k-offset within chunk
    const int lane = tid & 63, wv = tid >> 6;
    const int quad = lane >> 4, mrow = lane & 15;

    f32x4 acc0 = {0,0,0,0}, acc1 = {0,0,0,0}, acc2 = {0,0,0,0}, acc3 = {0,0,0,0};

    const unsigned short* arow = A + (size_t)(bm + r) * lda;
    const unsigned short* wrow = W + (size_t)(bn + r) * ldw;

    // prologue: stage iter 0 (chunks 0,1) into buf 0
    load_lds16(arow + kc,       As + tid * 8);
    load_lds16(arow + 32 + kc,  As + 2048 + tid * 8);
    load_lds16(wrow + kc,       Ws + tid * 8);
    load_lds16(wrow + 32 + kc,  Ws + 2048 + tid * 8);

    const int NI = K >> 6;    // K=512 -> 8 iterations
    for (int i = 0; i < NI; ++i) {
        const int cur = (i & 1) * 4096;
        if (i + 1 < NI) {
            const int nxt = 4096 - cur;
            int gk = ((i + 1) << 6) + kc;
            load_lds16(arow + gk,      As + nxt + tid * 8);
            load_lds16(arow + gk + 32, As + nxt + 2048 + tid * 8);
            load_lds16(wrow + gk,      Ws + nxt + tid * 8);
            load_lds16(wrow + gk + 32, Ws + nxt + 2048 + tid * 8);
            asm volatile("s_waitcnt vmcnt(4)" ::: "memory");   // iter i done
        } else {
            asm volatile("s_waitcnt vmcnt(0)" ::: "memory");
        }
        __builtin_amdgcn_s_barrier();          // iter-i LDS ready for all waves
        __builtin_amdgcn_sched_barrier(0);     // keep ds_reads below barrier
        #pragma unroll
        for (int h = 0; h < 2; ++h) {
            const unsigned short* Ab = As + cur + h * 2048;
            const unsigned short* Wb = Ws + cur + h * 2048;
            short8 av = *(const short8*)(Ab + (wv * 16 + mrow) * 32 + quad * 8);
            short8 b0 = *(const short8*)(Wb + (mrow) * 32 + quad * 8);
            short8 b1 = *(const short8*)(Wb + (16 + mrow) * 32 + quad * 8);
            short8 b2 = *(const short8*)(Wb + (32 + mrow) * 32 + quad * 8);
            short8 b3 = *(const short8*)(Wb + (48 + mrow) * 32 + quad * 8);
            acc0 = __builtin_amdgcn_mfma_f32_16x16x32_bf16(av, b0, acc0, 0, 0, 0);
            acc1 = __builtin_amdgcn_mfma_f32_16x16x32_bf16(av, b1, acc1, 0, 0, 0);
            acc2 = __builtin_amdgcn_mfma_f32_16x16x32_bf16(av, b2, acc2, 0, 0, 0);
            acc3 = __builtin_amdgcn_mfma_f32_16x16x32_bf16(av, b3, acc3, 0, 0, 0);
        }
        __builtin_amdgcn_sched_barrier(0);     // reads complete before barrier
        __builtin_amdgcn_s_barrier();          // safe to overwrite other buf
    }

    f32x4 accs[4] = {acc0, acc1, acc2, acc3};
    #pragma unroll
    for (int ct = 0; ct < 4; ++ct) {
        int col = bn + ct * 16 + mrow;
        float bv = bias ? bias[col] : 0.0f;
        #pragma unroll
        for (int rg = 0; rg < 4; ++rg) {
            int rw = bm + wv * 16 + quad * 4 + rg;   // C/D: col=lane&15, row=quad*4+reg
            float val = accs[ct][rg] + bv;
            if (outF) outF[(size_t)rw * N + col] = val;
            else      outB[(size_t)rw * N + col] = f2bf(val);
        }
    }
}

// ---------------- fused projections: 4 segments, 576 blocks -----------------
__global__ __launch_bounds__(256) void proj_gemm(
    const unsigned short* __restrict__ inputs_bf,
    const unsigned short* __restrict__ mems_bf,
    const unsigned short* __restrict__ Wq_bf,
    const unsigned short* __restrict__ Wc_bf,
    const float* __restrict__ bc,
    const unsigned short* __restrict__ Wout_bf,
    const float* __restrict__ bout,
    unsigned short* __restrict__ wq_o, unsigned short* __restrict__ uh_o,
    unsigned short* __restrict__ m2_o, float* __restrict__ ih_o)
{
    __shared__ __align__(16) unsigned short As[2 * 4096];
    __shared__ __align__(16) unsigned short Ws[2 * 4096];
    int bid = blockIdx.x;
    if (bid < 96) {
        gemm_tile(As, Ws, inputs_bf, DIN, Wq_bf, DIN, nullptr, nullptr, wq_o,
                  (bid >> 3) * 64, (bid & 7) * 64, DM, DIN);
    } else if (bid < 288) {
        bid -= 96;
        gemm_tile(As, Ws, mems_bf, DM, Wc_bf, DM, bc, nullptr, uh_o,
                  (bid >> 3) * 64, (bid & 7) * 64, DM, DM);
    } else if (bid < 480) {
        bid -= 288;
        gemm_tile(As, Ws, mems_bf, DM, Wout_bf, DM + DIN, nullptr, nullptr, m2_o,
                  (bid >> 3) * 64, (bid & 7) * 64, DM, DM);
    } else {
        bid -= 480;
        gemm_tile(As, Ws, inputs_bf, DIN, Wout_bf + DM, DM + DIN, bout, ih_o, nullptr,
                  (bid >> 3) * 64, (bid & 7) * 64, DIN, DIN);
    }
}

// ---------------- fused scores + softmax + context(M2) + ih add -------------
// scores: FOUR s-values per wave-iteration (s, s+4, s+8, s+12), independent
// loads + independent reduce chains -> 4x memory-level parallelism.
__global__ __launch_bounds__(256) void attn_core(
    const unsigned short* __restrict__ wq,     // [B*T][DM] bf16
    const unsigned short* __restrict__ uh,     // [B*S][DM] bf16
    const float* __restrict__ v,               // [DM] fp32
    const unsigned short* __restrict__ m2,     // [B*S][DM] bf16
    const float* __restrict__ ih,              // [B*T][DIN] fp32 (incl bout)
    const int* __restrict__ masks,             // [B]
    float* __restrict__ align_out,             // [B*T][S] fp32
    float* __restrict__ attn_h)                // [B*T][DIN] fp32
{
    __shared__ float s_align[SS];
    __shared__ __align__(16) float s_part[4][DM];
    __shared__ float s_stat;
    const int row = blockIdx.x, b = row / TT;
    const int tid = threadIdx.x, lane = tid & 63, wid = tid >> 6;
    const int len = masks[b];
    const float C = 2.885390082f;   // 2/ln2

    // masked tail of s_align -> -INF (writers disjoint from scores loop)
    if (tid >= len && tid < SS) s_align[tid] = -INFINITY;

    float cqf[8], vf[8];
    {
        short8 q = *(const short8*)(wq + (size_t)row * DM + lane * 8);
        float4 v0 = *(const float4*)(v + lane * 8);
        float4 v1 = *(const float4*)(v + lane * 8 + 4);
        #pragma unroll
        for (int j = 0; j < 8; ++j) cqf[j] = bf2f((unsigned short)q[j]) * C;
        vf[0] = v0.x; vf[1] = v0.y; vf[2] = v0.z; vf[3] = v0.w;
        vf[4] = v1.x; vf[5] = v1.y; vf[6] = v1.z; vf[7] = v1.w;
    }
    float SV = ((vf[0] + vf[1]) + (vf[2] + vf[3])) +
               ((vf[4] + vf[5]) + (vf[6] + vf[7]));
    #pragma unroll
    for (int off = 32; off; off >>= 1) SV += __shfl_xor(SV, off);

    const unsigned short* ub = uh + (size_t)b * SS * DM + lane * 8;
    for (int s = wid; s < len; s += 16) {
        const int sA = s + 4, sB = s + 8, sC = s + 12;
        const bool hA = sA < len, hB = sB < len, hC = sC < len;
        short8 u0 = *(const short8*)(ub + (size_t)s * DM);
        short8 u1 = hA ? *(const short8*)(ub + (size_t)sA * DM) : u0;
        short8 u2 = hB ? *(const short8*)(ub + (size_t)sB * DM) : u0;
        short8 u3 = hC ? *(const short8*)(ub + (size_t)sC * DM) : u0;
        float pr0 = 0.f, pr1 = 0.f, pr2 = 0.f, pr3 = 0.f;
        #pragma unroll
        for (int j = 0; j < 8; ++j) {
            float e0 = __builtin_amdgcn_exp2f(fmaf(bf2f((unsigned short)u0[j]), C, cqf[j]));
            float e1 = __builtin_amdgcn_exp2f(fmaf(bf2f((unsigned short)u1[j]), C, cqf[j]));
            float e2 = __builtin_amdgcn_exp2f(fmaf(bf2f((unsigned short)u2[j]), C, cqf[j]));
            float e3 = __builtin_amdgcn_exp2f(fmaf(bf2f((unsigned short)u3[j]), C, cqf[j]));
            pr0 = fmaf(vf[j], __builtin_amdgcn_rcpf(e0 + 1.f), pr0);
            pr1 = fmaf(vf[j], __builtin_amdgcn_rcpf(e1 + 1.f), pr1);
            pr2 = fmaf(vf[j], __builtin_amdgcn_rcpf(e2 + 1.f), pr2);
            pr3 = fmaf(vf[j], __builtin_amdgcn_rcpf(e3 + 1.f), pr3);
        }
        #pragma unroll
        for (int off = 32; off; off >>= 1) {
            pr0 += __shfl_xor(pr0, off);
            pr1 += __shfl_xor(pr1, off);
            pr2 += __shfl_xor(pr2, off);
            pr3 += __shfl_xor(pr3, off);
        }
        if (lane == 0) {
            s_align[s] = fmaf(-2.f, pr0, SV);
            if (hA) s_align[sA] = fmaf(-2.f, pr1, SV);
            if (hB) s_align[sB] = fmaf(-2.f, pr2, SV);
            if (hC) s_align[sC] = fmaf(-2.f, pr3, SV);
        }
    }
    __syncthreads();

    if (tid < 64) {
        float m = fmaxf(fmaxf(s_align[tid], s_align[tid + 64]), s_align[tid + 128]);
        #pragma unroll
        for (int off = 32; off; off >>= 1) m = fmaxf(m, __shfl_xor(m, off));
        float e0 = __builtin_amdgcn_exp2f((s_align[tid]       - m) * 1.44269504f);
        float e1 = __builtin_amdgcn_exp2f((s_align[tid + 64]  - m) * 1.44269504f);
        float e2 = __builtin_amdgcn_exp2f((s_align[tid + 128] - m) * 1.44269504f);
        s_align[tid] = e0; s_align[tid + 64] = e1; s_align[tid + 128] = e2;
        float sum = e0 + e1 + e2;
        #pragma unroll
        for (int off = 32; off; off >>= 1) sum += __shfl_xor(sum, off);
        if (tid == 0) s_stat = 1.0f / sum;
    }
    __syncthreads();
    const float inv = s_stat;
    if (tid < SS) align_out[(size_t)row * SS + tid] = s_align[tid] * inv;

    // ---- context partials: wave wid covers s in [wid*48, wid*48+nloc) ----
    const int sbase = wid * 48;
    int nloc = len - sbase;
    nloc = nloc < 0 ? 0 : (nloc > 48 ? 48 : nloc);
    float accv[8] = {0,0,0,0,0,0,0,0};
    const unsigned short* m2b = m2 + ((size_t)b * SS + sbase) * DM + lane * 8;
    #pragma unroll 8
    for (int i = 0; i < nloc; ++i) {
        float p = s_align[sbase + i];
        short8 mv = *(const short8*)(m2b + (size_t)i * DM);
        #pragma unroll
        for (int j = 0; j < 8; ++j)
            accv[j] = fmaf(p, bf2f((unsigned short)mv[j]), accv[j]);
    }
    {
        float4 t0; t0.x = accv[0]; t0.y = accv[1]; t0.z = accv[2]; t0.w = accv[3];
        float4 t1; t1.x = accv[4]; t1.y = accv[5]; t1.z = accv[6]; t1.w = accv[7];
        *(float4*)&s_part[wid][lane * 8]     = t0;
        *(float4*)&s_part[wid][lane * 8 + 4] = t1;
    }
    __syncthreads();

    const int d0 = tid * 2;
    float r0 = s_part[0][d0]     + s_part[1][d0]     + s_part[2][d0]     + s_part[3][d0];
    float r1 = s_part[0][d0 + 1] + s_part[1][d0 + 1] + s_part[2][d0 + 1] + s_part[3][d0 + 1];
    float2 ihv = *(const float2*)(ih + (size_t)row * DIN + d0);
    float2 o;
    o.x = fmaf(r0, inv, ihv.x);
    o.y = fmaf(r1, inv, ihv.y);
    *(float2*)(attn_h + (size_t)row * DIN + d0) = o;
}

extern "C" void kernel_launch(void* const* d_in, const int* in_sizes, int n_in,
                              void* d_out, int out_size, void* d_ws, size_t ws_size,
                              hipStream_t stream) {
    (void)in_sizes; (void)n_in; (void)out_size; (void)ws_size;
    const float* inputs = (const float*)d_in[0];
    const float* mems   = (const float*)d_in[1];
    const int*   masks  = (const int*)  d_in[2];
    const float* Wq     = (const float*)d_in[3];
    const float* Wc     = (const float*)d_in[4];
    const float* bc     = (const float*)d_in[5];
    const float* v      = (const float*)d_in[6];
    const float* Wout   = (const float*)d_in[7];
    const float* bout   = (const float*)d_in[8];

    unsigned short* p = (unsigned short*)d_ws;
    unsigned short* inputs_bf = p;        p += 393216;   // B*T*DIN
    unsigned short* mems_bf   = p;        p += 786432;   // B*S*DM
    unsigned short* Wq_bf     = p;        p += 262144;
    unsigned short* Wc_bf     = p;        p += 262144;
    unsigned short* Wout_bf   = p;        p += 524288;
    unsigned short* uh_bf     = p;        p += 786432;
    unsigned short* wq_bf     = p;        p += 393216;
    unsigned short* m2_bf     = p;        p += 786432;
    float* ih                 = (float*)p;               // [768][512] fp32, 16B-aligned

    float* attn_h    = (float*)d_out;                    // [768][512]
    float* align_out = attn_h + (size_t)BB * TT * DIN;   // [768][192]

    prep_cvt<<<1088, 256, 0, stream>>>(inputs, mems, Wq, Wc, Wout,
                                       inputs_bf, mems_bf, Wq_bf, Wc_bf, Wout_bf);
    proj_gemm<<<576, 256, 0, stream>>>(inputs_bf, mems_bf, Wq_bf, Wc_bf, bc,
                                       Wout_bf, bout, wq_bf, uh_bf, m2_bf, ih);
    attn_core<<<BB * TT, 256, 0, stream>>>(wq_bf, uh_bf, v, m2_bf, ih, masks,
                                           align_out, attn_h);
}

// Round 11
// 105.663 us; speedup vs baseline: 3.0070x; 1.0090x over previous
//
#include <hip/hip_runtime.h>
#include <math.h>

#define BB 8
#define TT 96
#define SS 192
#define DIN 512
#define DM 512

typedef short short8 __attribute__((ext_vector_type(8)));
typedef float f32x4 __attribute__((ext_vector_type(4)));

__device__ __forceinline__ unsigned short f2bf(float f) {
    unsigned int u = __float_as_uint(f);
    unsigned int r = u + 0x7FFFu + ((u >> 16) & 1u);   // RNE
    return (unsigned short)(r >> 16);
}
__device__ __forceinline__ float bf2f(unsigned short h) {
    return __uint_as_float(((unsigned int)h) << 16);
}

__device__ __forceinline__ void load_lds16(const void* g, void* l) {
    __builtin_amdgcn_global_load_lds((__attribute__((address_space(1))) void*)g,
                                     (__attribute__((address_space(3))) void*)l,
                                     16, 0, 0);
}

// ---------------- prep: fp32 -> bf16 conversion of 5 arrays ----------------
__global__ __launch_bounds__(256) void prep_cvt(
    const float* __restrict__ s0, const float* __restrict__ s1,
    const float* __restrict__ s2, const float* __restrict__ s3,
    const float* __restrict__ s4,
    unsigned short* __restrict__ d0, unsigned short* __restrict__ d1,
    unsigned short* __restrict__ d2, unsigned short* __restrict__ d3,
    unsigned short* __restrict__ d4)
{
    int bid = blockIdx.x;
    const float* s; unsigned short* d; int base;
    if (bid < 192)      { s = s0; d = d0; base = bid * 2048; }
    else if (bid < 576) { s = s1; d = d1; base = (bid - 192) * 2048; }
    else if (bid < 704) { s = s2; d = d2; base = (bid - 576) * 2048; }
    else if (bid < 832) { s = s3; d = d3; base = (bid - 704) * 2048; }
    else                { s = s4; d = d4; base = (bid - 832) * 2048; }
    int idx = base + threadIdx.x * 8;
    float4 a = *(const float4*)(s + idx);
    float4 b = *(const float4*)(s + idx + 4);
    short8 o;
    o[0] = (short)f2bf(a.x); o[1] = (short)f2bf(a.y);
    o[2] = (short)f2bf(a.z); o[3] = (short)f2bf(a.w);
    o[4] = (short)f2bf(b.x); o[5] = (short)f2bf(b.y);
    o[6] = (short)f2bf(b.z); o[7] = (short)f2bf(b.w);
    *(short8*)(d + idx) = o;
}

// ---------------- bf16 MFMA GEMM tile: BK=64, double-buffered, counted ------
// (R10-proven; unchanged)
__device__ __forceinline__ void gemm_tile(
    unsigned short* As, unsigned short* Ws,   // shared, 2*4096 ushorts each
    const unsigned short* __restrict__ A, int lda,
    const unsigned short* __restrict__ W, int ldw,
    const float* __restrict__ bias,
    float* __restrict__ outF, unsigned short* __restrict__ outB,
    int bm, int bn, int N, int K)
{
    const int tid = threadIdx.x;
    const int r  = tid >> 2;
    const int kc = (tid & 3) * 8;
    const int lane = tid & 63, wv = tid >> 6;
    const int quad = lane >> 4, mrow = lane & 15;

    f32x4 acc0 = {0,0,0,0}, acc1 = {0,0,0,0}, acc2 = {0,0,0,0}, acc3 = {0,0,0,0};

    const unsigned short* arow = A + (size_t)(bm + r) * lda;
    const unsigned short* wrow = W + (size_t)(bn + r) * ldw;

    load_lds16(arow + kc,       As + tid * 8);
    load_lds16(arow + 32 + kc,  As + 2048 + tid * 8);
    load_lds16(wrow + kc,       Ws + tid * 8);
    load_lds16(wrow + 32 + kc,  Ws + 2048 + tid * 8);

    const int NI = K >> 6;    // K=512 -> 8 iterations
    for (int i = 0; i < NI; ++i) {
        const int cur = (i & 1) * 4096;
        if (i + 1 < NI) {
            const int nxt = 4096 - cur;
            int gk = ((i + 1) << 6) + kc;
            load_lds16(arow + gk,      As + nxt + tid * 8);
            load_lds16(arow + gk + 32, As + nxt + 2048 + tid * 8);
            load_lds16(wrow + gk,      Ws + nxt + tid * 8);
            load_lds16(wrow + gk + 32, Ws + nxt + 2048 + tid * 8);
            asm volatile("s_waitcnt vmcnt(4)" ::: "memory");   // iter i done
        } else {
            asm volatile("s_waitcnt vmcnt(0)" ::: "memory");
        }
        __builtin_amdgcn_s_barrier();
        __builtin_amdgcn_sched_barrier(0);
        #pragma unroll
        for (int h = 0; h < 2; ++h) {
            const unsigned short* Ab = As + cur + h * 2048;
            const unsigned short* Wb = Ws + cur + h * 2048;
            short8 av = *(const short8*)(Ab + (wv * 16 + mrow) * 32 + quad * 8);
            short8 b0 = *(const short8*)(Wb + (mrow) * 32 + quad * 8);
            short8 b1 = *(const short8*)(Wb + (16 + mrow) * 32 + quad * 8);
            short8 b2 = *(const short8*)(Wb + (32 + mrow) * 32 + quad * 8);
            short8 b3 = *(const short8*)(Wb + (48 + mrow) * 32 + quad * 8);
            acc0 = __builtin_amdgcn_mfma_f32_16x16x32_bf16(av, b0, acc0, 0, 0, 0);
            acc1 = __builtin_amdgcn_mfma_f32_16x16x32_bf16(av, b1, acc1, 0, 0, 0);
            acc2 = __builtin_amdgcn_mfma_f32_16x16x32_bf16(av, b2, acc2, 0, 0, 0);
            acc3 = __builtin_amdgcn_mfma_f32_16x16x32_bf16(av, b3, acc3, 0, 0, 0);
        }
        __builtin_amdgcn_sched_barrier(0);
        __builtin_amdgcn_s_barrier();
    }

    f32x4 accs[4] = {acc0, acc1, acc2, acc3};
    #pragma unroll
    for (int ct = 0; ct < 4; ++ct) {
        int col = bn + ct * 16 + mrow;
        float bv = bias ? bias[col] : 0.0f;
        #pragma unroll
        for (int rg = 0; rg < 4; ++rg) {
            int rw = bm + wv * 16 + quad * 4 + rg;   // C/D: col=lane&15, row=quad*4+reg
            float val = accs[ct][rg] + bv;
            if (outF) outF[(size_t)rw * N + col] = val;
            else      outB[(size_t)rw * N + col] = f2bf(val);
        }
    }
}

// ---------------- fused projections: 4 segments, 576 blocks -----------------
__global__ __launch_bounds__(256) void proj_gemm(
    const unsigned short* __restrict__ inputs_bf,
    const unsigned short* __restrict__ mems_bf,
    const unsigned short* __restrict__ Wq_bf,
    const unsigned short* __restrict__ Wc_bf,
    const float* __restrict__ bc,
    const unsigned short* __restrict__ Wout_bf,
    const float* __restrict__ bout,
    unsigned short* __restrict__ wq_o, unsigned short* __restrict__ uh_o,
    unsigned short* __restrict__ m2_o, float* __restrict__ ih_o)
{
    __shared__ __align__(16) unsigned short As[2 * 4096];
    __shared__ __align__(16) unsigned short Ws[2 * 4096];
    int bid = blockIdx.x;
    if (bid < 96) {
        gemm_tile(As, Ws, inputs_bf, DIN, Wq_bf, DIN, nullptr, nullptr, wq_o,
                  (bid >> 3) * 64, (bid & 7) * 64, DM, DIN);
    } else if (bid < 288) {
        bid -= 96;
        gemm_tile(As, Ws, mems_bf, DM, Wc_bf, DM, bc, nullptr, uh_o,
                  (bid >> 3) * 64, (bid & 7) * 64, DM, DM);
    } else if (bid < 480) {
        bid -= 288;
        gemm_tile(As, Ws, mems_bf, DM, Wout_bf, DM + DIN, nullptr, nullptr, m2_o,
                  (bid >> 3) * 64, (bid & 7) * 64, DM, DM);
    } else {
        bid -= 480;
        gemm_tile(As, Ws, inputs_bf, DIN, Wout_bf + DM, DM + DIN, bout, ih_o, nullptr,
                  (bid >> 3) * 64, (bid & 7) * 64, DIN, DIN);
    }
}

// ---------------- fused scores + softmax + context(M2) + ih add -------------
// scores: EIGHT s-values per wave-iteration (s+4k, k=0..7), independent loads
// + independent trans chains + interleaved reduce -> compute fully covers the
// load-batch latency (3 iters/wave at E[len]=96). All array indices
// compile-time after full unroll.
__global__ __launch_bounds__(256) void attn_core(
    const unsigned short* __restrict__ wq,     // [B*T][DM] bf16
    const unsigned short* __restrict__ uh,     // [B*S][DM] bf16
    const float* __restrict__ v,               // [DM] fp32
    const unsigned short* __restrict__ m2,     // [B*S][DM] bf16
    const float* __restrict__ ih,              // [B*T][DIN] fp32 (incl bout)
    const int* __restrict__ masks,             // [B]
    float* __restrict__ align_out,             // [B*T][S] fp32
    float* __restrict__ attn_h)                // [B*T][DIN] fp32
{
    __shared__ float s_align[SS];
    __shared__ __align__(16) float s_part[4][DM];
    __shared__ float s_stat;
    const int row = blockIdx.x, b = row / TT;
    const int tid = threadIdx.x, lane = tid & 63, wid = tid >> 6;
    const int len = masks[b];
    const float C = 2.885390082f;   // 2/ln2

    // masked tail of s_align -> -INF (writers disjoint from scores loop)
    if (tid >= len && tid < SS) s_align[tid] = -INFINITY;

    float cqf[8], vf[8];
    {
        short8 q = *(const short8*)(wq + (size_t)row * DM + lane * 8);
        float4 v0 = *(const float4*)(v + lane * 8);
        float4 v1 = *(const float4*)(v + lane * 8 + 4);
        #pragma unroll
        for (int j = 0; j < 8; ++j) cqf[j] = bf2f((unsigned short)q[j]) * C;
        vf[0] = v0.x; vf[1] = v0.y; vf[2] = v0.z; vf[3] = v0.w;
        vf[4] = v1.x; vf[5] = v1.y; vf[6] = v1.z; vf[7] = v1.w;
    }
    float SV = ((vf[0] + vf[1]) + (vf[2] + vf[3])) +
               ((vf[4] + vf[5]) + (vf[6] + vf[7]));
    #pragma unroll
    for (int off = 32; off; off >>= 1) SV += __shfl_xor(SV, off);

    const unsigned short* ub = uh + (size_t)b * SS * DM + lane * 8;
    for (int s = wid; s < len; s += 32) {
        short8 u[8];
        float pr[8];
        #pragma unroll
        for (int k = 0; k < 8; ++k) {
            int si = s + 4 * k;
            int sc = si < len ? si : s;          // clamp to a valid row
            u[k] = *(const short8*)(ub + (size_t)sc * DM);
            pr[k] = 0.f;
        }
        #pragma unroll
        for (int j = 0; j < 8; ++j) {
            #pragma unroll
            for (int k = 0; k < 8; ++k) {
                float e = __builtin_amdgcn_exp2f(
                    fmaf(bf2f((unsigned short)u[k][j]), C, cqf[j]));
                pr[k] = fmaf(vf[j], __builtin_amdgcn_rcpf(e + 1.f), pr[k]);
            }
        }
        #pragma unroll
        for (int off = 32; off; off >>= 1) {
            #pragma unroll
            for (int k = 0; k < 8; ++k)
                pr[k] += __shfl_xor(pr[k], off);
        }
        if (lane == 0) {
            #pragma unroll
            for (int k = 0; k < 8; ++k) {
                int si = s + 4 * k;
                if (si < len) s_align[si] = fmaf(-2.f, pr[k], SV);
            }
        }
    }
    __syncthreads();

    if (tid < 64) {
        float m = fmaxf(fmaxf(s_align[tid], s_align[tid + 64]), s_align[tid + 128]);
        #pragma unroll
        for (int off = 32; off; off >>= 1) m = fmaxf(m, __shfl_xor(m, off));
        float e0 = __builtin_amdgcn_exp2f((s_align[tid]       - m) * 1.44269504f);
        float e1 = __builtin_amdgcn_exp2f((s_align[tid + 64]  - m) * 1.44269504f);
        float e2 = __builtin_amdgcn_exp2f((s_align[tid + 128] - m) * 1.44269504f);
        s_align[tid] = e0; s_align[tid + 64] = e1; s_align[tid + 128] = e2;
        float sum = e0 + e1 + e2;
        #pragma unroll
        for (int off = 32; off; off >>= 1) sum += __shfl_xor(sum, off);
        if (tid == 0) s_stat = 1.0f / sum;
    }
    __syncthreads();
    const float inv = s_stat;
    if (tid < SS) align_out[(size_t)row * SS + tid] = s_align[tid] * inv;

    // ---- context partials: wave wid covers s in [wid*48, wid*48+nloc) ----
    const int sbase = wid * 48;
    int nloc = len - sbase;
    nloc = nloc < 0 ? 0 : (nloc > 48 ? 48 : nloc);
    float accv[8] = {0,0,0,0,0,0,0,0};
    const unsigned short* m2b = m2 + ((size_t)b * SS + sbase) * DM + lane * 8;
    #pragma unroll 8
    for (int i = 0; i < nloc; ++i) {
        float p = s_align[sbase + i];
        short8 mv = *(const short8*)(m2b + (size_t)i * DM);
        #pragma unroll
        for (int j = 0; j < 8; ++j)
            accv[j] = fmaf(p, bf2f((unsigned short)mv[j]), accv[j]);
    }
    {
        float4 t0; t0.x = accv[0]; t0.y = accv[1]; t0.z = accv[2]; t0.w = accv[3];
        float4 t1; t1.x = accv[4]; t1.y = accv[5]; t1.z = accv[6]; t1.w = accv[7];
        *(float4*)&s_part[wid][lane * 8]     = t0;
        *(float4*)&s_part[wid][lane * 8 + 4] = t1;
    }
    __syncthreads();

    const int d0 = tid * 2;
    float r0 = s_part[0][d0]     + s_part[1][d0]     + s_part[2][d0]     + s_part[3][d0];
    float r1 = s_part[0][d0 + 1] + s_part[1][d0 + 1] + s_part[2][d0 + 1] + s_part[3][d0 + 1];
    float2 ihv = *(const float2*)(ih + (size_t)row * DIN + d0);
    float2 o;
    o.x = fmaf(r0, inv, ihv.x);
    o.y = fmaf(r1, inv, ihv.y);
    *(float2*)(attn_h + (size_t)row * DIN + d0) = o;
}

extern "C" void kernel_launch(void* const* d_in, const int* in_sizes, int n_in,
                              void* d_out, int out_size, void* d_ws, size_t ws_size,
                              hipStream_t stream) {
    (void)in_sizes; (void)n_in; (void)out_size; (void)ws_size;
    const float* inputs = (const float*)d_in[0];
    const float* mems   = (const float*)d_in[1];
    const int*   masks  = (const int*)  d_in[2];
    const float* Wq     = (const float*)d_in[3];
    const float* Wc     = (const float*)d_in[4];
    const float* bc     = (const float*)d_in[5];
    const float* v      = (const float*)d_in[6];
    const float* Wout   = (const float*)d_in[7];
    const float* bout   = (const float*)d_in[8];

    unsigned short* p = (unsigned short*)d_ws;
    unsigned short* inputs_bf = p;        p += 393216;   // B*T*DIN
    unsigned short* mems_bf   = p;        p += 786432;   // B*S*DM
    unsigned short* Wq_bf     = p;        p += 262144;
    unsigned short* Wc_bf     = p;        p += 262144;
    unsigned short* Wout_bf   = p;        p += 524288;
    unsigned short* uh_bf     = p;        p += 786432;
    unsigned short* wq_bf     = p;        p += 393216;
    unsigned short* m2_bf     = p;        p += 786432;
    float* ih                 = (float*)p;               // [768][512] fp32, 16B-aligned

    float* attn_h    = (float*)d_out;                    // [768][512]
    float* align_out = attn_h + (size_t)BB * TT * DIN;   // [768][192]

    prep_cvt<<<1088, 256, 0, stream>>>(inputs, mems, Wq, Wc, Wout,
                                       inputs_bf, mems_bf, Wq_bf, Wc_bf, Wout_bf);
    proj_gemm<<<576, 256, 0, stream>>>(inputs_bf, mems_bf, Wq_bf, Wc_bf, bc,
                                       Wout_bf, bout, wq_bf, uh_bf, m2_bf, ih);
    attn_core<<<BB * TT, 256, 0, stream>>>(wq_bf, uh_bf, v, m2_bf, ih, masks,
                                           align_out, attn_h);
}